// Round 4
// baseline (221.489 us; speedup 1.0000x reference)
//
#include <hip/hip_runtime.h>
#include <hip/hip_bf16.h>
#include <math.h>

#define BB 4
#define CC 128
#define HH 128
#define WW 128
#define OO 256
#define HWP 16384   // H*W

typedef __attribute__((ext_vector_type(8))) short short8;   // bf16x8 MFMA frag
typedef __attribute__((ext_vector_type(4))) float floatx4;  // MFMA C/D frag

__device__ inline float bf2f(unsigned short u) {
  union { unsigned int i; float f; } z; z.i = ((unsigned)u) << 16; return z.f;
}
__device__ inline unsigned short f2bf_bits(float f) {
  return __bfloat16_as_ushort(__float2bfloat16(f));
}

// ---------------------------------------------------------------------------
// P1: fused NCHW->NHWC bf16 hi/lo transpose (z<4) + weight prep (z==4).
// Transpose writes packed uint (2 bf16) per lane: 256 B per store inst.
// ---------------------------------------------------------------------------
__global__ __launch_bounds__(256) void k_transpose(const float* __restrict__ x,
                                                   const float* __restrict__ w_off,
                                                   const float* __restrict__ w_pw,
                                                   unsigned int* __restrict__ xh32,
                                                   unsigned int* __restrict__ xl32,
                                                   __hip_bfloat16* __restrict__ Ahi,
                                                   __hip_bfloat16* __restrict__ Alo,
                                                   __hip_bfloat16* __restrict__ Apw) {
  int tid = threadIdx.x;
  if (blockIdx.z == 4) {
    // ---- weight prep ----
    int e = (blockIdx.x * 128 + blockIdx.y) * 256 + tid;
    if (e < 144 * 32 * 8) {
      int kblk = e >> 8;
      int o = (e >> 3) & 31;
      int j = e & 7;
      int k = kblk * 8 + j;
      int t = k >> 7, c = k & 127;
      float w = (o < 27) ? w_off[(o * CC + c) * 9 + t] : 0.0f;
      __hip_bfloat16 hv = __float2bfloat16(w);
      Ahi[e] = hv;
      Alo[e] = __float2bfloat16(w - __bfloat162float(hv));
    }
    int e2 = e - 144 * 32 * 8;
    if (e2 >= 0 && e2 < 16 * 256 * 8) {
      int cblk = e2 >> 11;
      int o = (e2 >> 3) & 255;
      int j = e2 & 7;
      Apw[e2] = __float2bfloat16(w_pw[o * CC + cblk * 8 + j]);
    }
    return;
  }
  __shared__ float tile[64][65];   // [c'][w']
  int wt = blockIdx.x & 1;
  int ct = blockIdx.x >> 1;
  int h = blockIdx.y, b = blockIdx.z;
  int tw = tid & 63;
  int tc = tid >> 6;
#pragma unroll
  for (int i = 0; i < 16; i++) {
    int c = ct * 64 + i * 4 + tc;
    tile[i * 4 + tc][tw] = x[((b * CC + c) * HH + h) * WW + wt * 64 + tw];
  }
  __syncthreads();
  int cp = tid & 31;        // channel pair within 64-ch tile
  int wq = tid >> 5;        // 8 w-groups
#pragma unroll
  for (int i = 0; i < 8; i++) {
    int wp = i * 8 + wq;    // w' in [0,64)
    int w = wt * 64 + wp;
    float v0 = tile[cp * 2][wp];
    float v1 = tile[cp * 2 + 1][wp];
    unsigned short h0 = f2bf_bits(v0);
    unsigned short h1 = f2bf_bits(v1);
    unsigned short l0 = f2bf_bits(v0 - bf2f(h0));
    unsigned short l1 = f2bf_bits(v1 - bf2f(h1));
    int idx2 = (((b * HH + h) * WW + w) * CC + ct * 64 + cp * 2) >> 1;  // uint index
    xh32[idx2] = (unsigned int)h0 | ((unsigned int)h1 << 16);
    xl32[idx2] = (unsigned int)l0 | ((unsigned int)l1 << 16);
  }
}

// ---------------------------------------------------------------------------
// P2: offset conv as MFMA implicit GEMM (hi/lo split, drops lo.lo only).
// 1D grid 512, XCD-swizzled: xcd=bid&7 -> 16-row band of one image.
// ---------------------------------------------------------------------------
__global__ __launch_bounds__(256) void k_offconv_mfma(
    const __hip_bfloat16* __restrict__ xh, const __hip_bfloat16* __restrict__ xl,
    const __hip_bfloat16* __restrict__ Ahi, const __hip_bfloat16* __restrict__ Alo,
    const float* __restrict__ b_off, float* __restrict__ om) {
  int bid = blockIdx.x;
  int xcd = bid & 7, r = bid >> 3;
  int b = r >> 4;
  int h = xcd * 16 + (r & 15);
  int tid = threadIdx.x;
  int wv = tid >> 6, lane = tid & 63;
  int w0 = wv * 32;
  int n16 = lane & 15, quad = lane >> 4;

  floatx4 acc[2][2] = {};
  floatx4 acc2[2][2] = {};
  short8 zz = {};

  for (int t = 0; t < 9; t++) {
    int dy = t / 3 - 1, dx = t % 3 - 1;
    int hs = h + dy;
    bool hok = ((unsigned)hs < HH);
    int hsc = min(max(hs, 0), HH - 1);
    int wA = w0 + n16 + dx;
    int wB = wA + 16;
    bool okA = hok && ((unsigned)wA < WW);
    bool okB = hok && ((unsigned)wB < WW);
    int wAc = min(max(wA, 0), WW - 1);
    int wBc = min(max(wB, 0), WW - 1);
    size_t offA = (size_t)((b * HH + hsc) * WW + wAc) * CC + quad * 8;
    size_t offB = (size_t)((b * HH + hsc) * WW + wBc) * CC + quad * 8;
#pragma unroll
    for (int cs = 0; cs < 4; cs++) {
      int co = cs * 32;
      short8 bhA = *(const short8*)(xh + offA + co);
      short8 bhB = *(const short8*)(xh + offB + co);
      short8 blA = *(const short8*)(xl + offA + co);
      short8 blB = *(const short8*)(xl + offB + co);
      bhA = okA ? bhA : zz;  blA = okA ? blA : zz;
      bhB = okB ? bhB : zz;  blB = okB ? blB : zz;
      int kblk = t * 16 + cs * 4 + quad;
      const short* pa = (const short*)Ahi + (size_t)kblk * 256 + n16 * 8;
      const short* pl = (const short*)Alo + (size_t)kblk * 256 + n16 * 8;
      short8 a0 = *(const short8*)pa;
      short8 a1 = *(const short8*)(pa + 128);
      short8 l0 = *(const short8*)pl;
      short8 l1 = *(const short8*)(pl + 128);
      acc[0][0] = __builtin_amdgcn_mfma_f32_16x16x32_bf16(a0, bhA, acc[0][0], 0, 0, 0);
      acc[1][0] = __builtin_amdgcn_mfma_f32_16x16x32_bf16(a1, bhA, acc[1][0], 0, 0, 0);
      acc[0][1] = __builtin_amdgcn_mfma_f32_16x16x32_bf16(a0, bhB, acc[0][1], 0, 0, 0);
      acc[1][1] = __builtin_amdgcn_mfma_f32_16x16x32_bf16(a1, bhB, acc[1][1], 0, 0, 0);
      acc[0][0] = __builtin_amdgcn_mfma_f32_16x16x32_bf16(a0, blA, acc[0][0], 0, 0, 0);
      acc[1][0] = __builtin_amdgcn_mfma_f32_16x16x32_bf16(a1, blA, acc[1][0], 0, 0, 0);
      acc[0][1] = __builtin_amdgcn_mfma_f32_16x16x32_bf16(a0, blB, acc[0][1], 0, 0, 0);
      acc[1][1] = __builtin_amdgcn_mfma_f32_16x16x32_bf16(a1, blB, acc[1][1], 0, 0, 0);
      acc2[0][0] = __builtin_amdgcn_mfma_f32_16x16x32_bf16(l0, bhA, acc2[0][0], 0, 0, 0);
      acc2[1][0] = __builtin_amdgcn_mfma_f32_16x16x32_bf16(l1, bhA, acc2[1][0], 0, 0, 0);
      acc2[0][1] = __builtin_amdgcn_mfma_f32_16x16x32_bf16(l0, bhB, acc2[0][1], 0, 0, 0);
      acc2[1][1] = __builtin_amdgcn_mfma_f32_16x16x32_bf16(l1, bhB, acc2[1][1], 0, 0, 0);
    }
  }
#pragma unroll
  for (int mt = 0; mt < 2; mt++) {
#pragma unroll
    for (int reg = 0; reg < 4; reg++) {
      int o = mt * 16 + quad * 4 + reg;
      if (o < 27) {
        float bo = b_off[o];
#pragma unroll
        for (int nf = 0; nf < 2; nf++) {
          int w = w0 + nf * 16 + n16;
          om[((size_t)(b * 27 + o) << 14) + (h << 7) + w] =
              acc[mt][nf][reg] + acc2[mt][nf][reg] + bo;
        }
      }
    }
  }
}

// ---------------------------------------------------------------------------
// P3: deformable sampling + mask + depthwise, gathering bf16 xh.
// All 36 corner loads hoisted into registers before the accumulate loop so a
// single latency exposure covers the whole gather (VGPR budget ~170 via
// launch_bounds(256,3)).
// ---------------------------------------------------------------------------
__global__ __launch_bounds__(256, 3) void k_sample(const unsigned short* __restrict__ xh,
                                                   const float* __restrict__ om,
                                                   const float* __restrict__ w_dw,
                                                   const float* __restrict__ b_dw,
                                                   unsigned short* __restrict__ out1b) {
  __shared__ int s_base[8][9], s_dxs[8][9], s_dys[8][9];
  __shared__ float s_w[8][9][4];
  int tid = threadIdx.x;
  int bid = blockIdx.x;
  int n0 = ((bid & 7) * 1024 + (bid >> 3)) * 8;   // XCD-contiguous bands
  if (tid < 72) {
    int pix = tid / 9, k = tid - pix * 9;
    int n = n0 + pix;
    int b = n >> 14, rem = n & 16383;
    int h = rem >> 7, w = rem & 127;
    const float* op = om + b * 27 * HWP + rem;
    float dy = op[(2 * k) * HWP];
    float dx = op[(2 * k + 1) * HWP];
    float mv = op[(18 + k) * HWP];
    mv = 1.0f / (1.0f + __expf(-mv));
    float py = (float)(h + k / 3 - 1) + dy;
    float px = (float)(w + k % 3 - 1) + dx;
    float y0f = floorf(py), x0f = floorf(px);
    float wy = py - y0f, wx = px - x0f;
    int y0 = (int)y0f, x0 = (int)x0f;
    int y1 = y0 + 1, x1 = x0 + 1;
    float v00 = (y0 >= 0 && y0 < HH && x0 >= 0 && x0 < WW) ? 1.f : 0.f;
    float v01 = (y0 >= 0 && y0 < HH && x1 >= 0 && x1 < WW) ? 1.f : 0.f;
    float v10 = (y1 >= 0 && y1 < HH && x0 >= 0 && x0 < WW) ? 1.f : 0.f;
    float v11 = (y1 >= 0 && y1 < HH && x1 >= 0 && x1 < WW) ? 1.f : 0.f;
    int y0c = min(max(y0, 0), HH - 1), y1c = min(max(y1, 0), HH - 1);
    int x0c = min(max(x0, 0), WW - 1), x1c = min(max(x1, 0), WW - 1);
    s_base[pix][k] = ((b * HH + y0c) * WW + x0c) * CC;
    s_dxs[pix][k] = (x1c - x0c) * CC;
    s_dys[pix][k] = (y1c - y0c) * WW * CC;
    s_w[pix][k][0] = (1.f - wy) * (1.f - wx) * mv * v00;
    s_w[pix][k][1] = (1.f - wy) * wx * mv * v01;
    s_w[pix][k][2] = wy * (1.f - wx) * mv * v10;
    s_w[pix][k][3] = wy * wx * mv * v11;
  }
  __syncthreads();
  int wv = tid >> 6, lane = tid & 63;
  int pix = wv * 2 + (lane >> 5);
  int cl = lane & 31;
  int c0 = cl * 4;
  int n = n0 + pix;

  // hoist ALL corner loads (9 taps x 4 corners, ushort4 each)
  ushort4 v[9][4];
#pragma unroll
  for (int k = 0; k < 9; k++) {
    int base = s_base[pix][k] + c0;
    int dxs = s_dxs[pix][k], dys = s_dys[pix][k];
    v[k][0] = *(const ushort4*)(xh + base);
    v[k][1] = *(const ushort4*)(xh + base + dxs);
    v[k][2] = *(const ushort4*)(xh + base + dys);
    v[k][3] = *(const ushort4*)(xh + base + dys + dxs);
  }
  // depthwise weights for channels c0..c0+3
  float4 wk4[9];
#pragma unroll
  for (int i = 0; i < 9; i++) wk4[i] = *(const float4*)(w_dw + c0 * 9 + i * 4);
  const float* wkf = (const float*)wk4;   // wkf[j*9 + k]

  float acc0 = 0.f, acc1 = 0.f, acc2v = 0.f, acc3 = 0.f;
#pragma unroll
  for (int k = 0; k < 9; k++) {
    float4 wgt = *(const float4*)s_w[pix][k];
    float s0 = wgt.x * bf2f(v[k][0].x) + wgt.y * bf2f(v[k][1].x) + wgt.z * bf2f(v[k][2].x) + wgt.w * bf2f(v[k][3].x);
    float s1 = wgt.x * bf2f(v[k][0].y) + wgt.y * bf2f(v[k][1].y) + wgt.z * bf2f(v[k][2].y) + wgt.w * bf2f(v[k][3].y);
    float s2 = wgt.x * bf2f(v[k][0].z) + wgt.y * bf2f(v[k][1].z) + wgt.z * bf2f(v[k][2].z) + wgt.w * bf2f(v[k][3].z);
    float s3 = wgt.x * bf2f(v[k][0].w) + wgt.y * bf2f(v[k][1].w) + wgt.z * bf2f(v[k][2].w) + wgt.w * bf2f(v[k][3].w);
    acc0 = fmaf(s0, wkf[0 * 9 + k], acc0);
    acc1 = fmaf(s1, wkf[1 * 9 + k], acc1);
    acc2v = fmaf(s2, wkf[2 * 9 + k], acc2v);
    acc3 = fmaf(s3, wkf[3 * 9 + k], acc3);
  }
  float4 bd = *(const float4*)(b_dw + c0);
  acc0 += bd.x; acc1 += bd.y; acc2v += bd.z; acc3 += bd.w;
  ushort4 ov;
  ov.x = f2bf_bits(acc0);
  ov.y = f2bf_bits(acc1);
  ov.z = f2bf_bits(acc2v);
  ov.w = f2bf_bits(acc3);
  *(ushort4*)(out1b + (size_t)n * CC + c0) = ov;
}

// ---------------------------------------------------------------------------
// P4: pointwise GEMM, bf16 MFMA. Block = 4 waves; block tile 256o x 64n.
// ---------------------------------------------------------------------------
__global__ __launch_bounds__(256) void k_pw_mfma(const __hip_bfloat16* __restrict__ Apw,
                                                 const unsigned short* __restrict__ out1b,
                                                 const float* __restrict__ bpw,
                                                 float* __restrict__ out) {
  int bid = blockIdx.x;
  int n0 = ((bid & 7) * 128 + (bid >> 3)) * 64;
  int tid = threadIdx.x;
  int wv = tid >> 6, lane = tid & 63;
  int n16 = lane & 15, quad = lane >> 4;
  int obase = wv * 64;

  floatx4 acc[4][4] = {};   // [mf][nf]
#pragma unroll
  for (int cs = 0; cs < 4; cs++) {
    short8 af[4], bf[4];
#pragma unroll
    for (int mf = 0; mf < 4; mf++) {
      const short* pa = (const short*)Apw + ((size_t)(cs * 4 + quad) * 256 + obase + mf * 16 + n16) * 8;
      af[mf] = *(const short8*)pa;
    }
#pragma unroll
    for (int nf = 0; nf < 4; nf++) {
      const short* pb = (const short*)out1b + (size_t)(n0 + nf * 16 + n16) * CC + cs * 32 + quad * 8;
      bf[nf] = *(const short8*)pb;
    }
#pragma unroll
    for (int mf = 0; mf < 4; mf++)
#pragma unroll
      for (int nf = 0; nf < 4; nf++)
        acc[mf][nf] = __builtin_amdgcn_mfma_f32_16x16x32_bf16(af[mf], bf[nf], acc[mf][nf], 0, 0, 0);
  }
  int b = n0 >> 14;
#pragma unroll
  for (int mf = 0; mf < 4; mf++) {
#pragma unroll
    for (int reg = 0; reg < 4; reg++) {
      int o = obase + mf * 16 + quad * 4 + reg;
      float bo = bpw[o];
#pragma unroll
      for (int nf = 0; nf < 4; nf++) {
        int n = n0 + nf * 16 + n16;
        int hw = n & 16383;
        out[((size_t)(b * OO + o) << 14) + hw] = acc[mf][nf][reg] + bo;
      }
    }
  }
}

// ---------------------------------------------------------------------------
extern "C" void kernel_launch(void* const* d_in, const int* in_sizes, int n_in,
                              void* d_out, int out_size, void* d_ws, size_t ws_size,
                              hipStream_t stream) {
  const float* x     = (const float*)d_in[0];
  const float* w_off = (const float*)d_in[1];
  const float* b_off = (const float*)d_in[2];
  const float* w_dw  = (const float*)d_in[3];
  const float* b_dw  = (const float*)d_in[4];
  const float* w_pw  = (const float*)d_in[5];
  const float* b_pw  = (const float*)d_in[6];
  float* out = (float*)d_out;
  float* ws  = (float*)d_ws;

  // d_out scratch (dead before k_pw_mfma writes): xh, xl bf16 NHWC
  __hip_bfloat16* xh = (__hip_bfloat16*)out;
  __hip_bfloat16* xl = xh + 8388608;

  // ws: om fp32 | out1b bf16 | Ahi | Alo | Apw
  float* om = ws;                                           // 1769472 floats
  unsigned short* out1b = (unsigned short*)(ws + 1769472);  // 8388608 bf16
  __hip_bfloat16* Ahi = (__hip_bfloat16*)(ws + 5963776);    // 36864
  __hip_bfloat16* Alo = Ahi + 36864;                        // 36864
  __hip_bfloat16* Apw = Alo + 36864;                        // 32768

  k_transpose<<<dim3(4, 128, 5), 256, 0, stream>>>(x, w_off, w_pw,
                                                   (unsigned int*)xh, (unsigned int*)xl,
                                                   Ahi, Alo, Apw);
  k_offconv_mfma<<<512, 256, 0, stream>>>(xh, xl, Ahi, Alo, b_off, om);
  k_sample<<<8192, 256, 0, stream>>>((const unsigned short*)xh, om, w_dw, b_dw, out1b);
  k_pw_mfma<<<1024, 256, 0, stream>>>(Apw, out1b, b_pw, out);
}

// Round 6
// 194.884 us; speedup vs baseline: 1.1365x; 1.1365x over previous
//
#include <hip/hip_runtime.h>
#include <hip/hip_bf16.h>
#include <math.h>

#define BB 4
#define CC 128
#define HH 128
#define WW 128
#define OO 256
#define HWP 16384   // H*W

typedef __attribute__((ext_vector_type(8))) _Float16 half8;   // f16x8 MFMA frag
typedef __attribute__((ext_vector_type(2))) _Float16 half2t;  // v_dot2 operand
typedef __attribute__((ext_vector_type(4))) float floatx4;    // MFMA C/D frag

__device__ inline half2t u2h2(unsigned int u) {
  union { unsigned int i; half2t h; } z; z.i = u; return z.h;
}
__device__ inline unsigned short f2h_bits(float f) {
  union { _Float16 h; unsigned short s; } z; z.h = (_Float16)f; return z.s;
}

// ---------------------------------------------------------------------------
// P1: fused NCHW->NHWC f16 transpose (z<4) + weight prep (z==4).
// ---------------------------------------------------------------------------
__global__ __launch_bounds__(256) void k_transpose(const float* __restrict__ x,
                                                   const float* __restrict__ w_off,
                                                   const float* __restrict__ w_pw,
                                                   unsigned int* __restrict__ xh32,
                                                   _Float16* __restrict__ Ah,
                                                   _Float16* __restrict__ Apw) {
  int tid = threadIdx.x;
  if (blockIdx.z == 4) {
    int e = (blockIdx.x * 128 + blockIdx.y) * 256 + tid;
    if (e < 144 * 32 * 8) {   // offconv A: [kblk=144][o=32][8], k = t*128+c
      int kblk = e >> 8;
      int o = (e >> 3) & 31;
      int j = e & 7;
      int k = kblk * 8 + j;
      int t = k >> 7, c = k & 127;
      float w = (o < 27) ? w_off[(o * CC + c) * 9 + t] : 0.0f;
      Ah[e] = (_Float16)w;
    }
    int e2 = e - 144 * 32 * 8;
    if (e2 >= 0 && e2 < 16 * 256 * 8) {   // pw A: [cblk=16][o=256][8]
      int cblk = e2 >> 11;
      int o = (e2 >> 3) & 255;
      int j = e2 & 7;
      Apw[e2] = (_Float16)w_pw[o * CC + cblk * 8 + j];
    }
    return;
  }
  __shared__ float tile[64][65];   // [c'][w']
  int wt = blockIdx.x & 1;
  int ct = blockIdx.x >> 1;
  int h = blockIdx.y, b = blockIdx.z;
  int tw = tid & 63;
  int tc = tid >> 6;
#pragma unroll
  for (int i = 0; i < 16; i++) {
    int c = ct * 64 + i * 4 + tc;
    tile[i * 4 + tc][tw] = x[((b * CC + c) * HH + h) * WW + wt * 64 + tw];
  }
  __syncthreads();
  int cp = tid & 31;        // channel pair within 64-ch tile
  int wq = tid >> 5;        // 8 w-groups
#pragma unroll
  for (int i = 0; i < 8; i++) {
    int wp = i * 8 + wq;    // w' in [0,64)
    int w = wt * 64 + wp;
    unsigned short h0 = f2h_bits(tile[cp * 2][wp]);
    unsigned short h1 = f2h_bits(tile[cp * 2 + 1][wp]);
    int idx2 = (((b * HH + h) * WW + w) * CC + ct * 64 + cp * 2) >> 1;
    xh32[idx2] = (unsigned int)h0 | ((unsigned int)h1 << 16);
  }
}

// ---------------------------------------------------------------------------
// P2: offset conv as f16 MFMA implicit GEMM (single precision term).
// Grid 512 XCD-swizzled; block = 4 waves = one image row; wave: 32 px x 32 o.
// Per k-chunk (32): 2 B-loads + 2 A-loads (16B) + 4 MFMA.
// ---------------------------------------------------------------------------
__global__ __launch_bounds__(256) void k_offconv_mfma(
    const _Float16* __restrict__ xh, const _Float16* __restrict__ Ah,
    const float* __restrict__ b_off, float* __restrict__ om) {
  int bid = blockIdx.x;
  int xcd = bid & 7, r = bid >> 3;
  int b = r >> 4;
  int h = xcd * 16 + (r & 15);
  int tid = threadIdx.x;
  int wv = tid >> 6, lane = tid & 63;
  int w0 = wv * 32;
  int n16 = lane & 15, quad = lane >> 4;

  floatx4 acc[2][2] = {};
  half8 zz = {};

  for (int t = 0; t < 9; t++) {
    int dy = t / 3 - 1, dx = t % 3 - 1;
    int hs = h + dy;
    bool hok = ((unsigned)hs < HH);
    int hsc = min(max(hs, 0), HH - 1);
    int wA = w0 + n16 + dx;
    int wB = wA + 16;
    bool okA = hok && ((unsigned)wA < WW);
    bool okB = hok && ((unsigned)wB < WW);
    int wAc = min(max(wA, 0), WW - 1);
    int wBc = min(max(wB, 0), WW - 1);
    size_t offA = (size_t)((b * HH + hsc) * WW + wAc) * CC + quad * 8;
    size_t offB = (size_t)((b * HH + hsc) * WW + wBc) * CC + quad * 8;
#pragma unroll
    for (int cs = 0; cs < 4; cs++) {
      int co = cs * 32;
      half8 bhA = *(const half8*)(xh + offA + co);
      half8 bhB = *(const half8*)(xh + offB + co);
      bhA = okA ? bhA : zz;
      bhB = okB ? bhB : zz;
      int kblk = t * 16 + cs * 4 + quad;
      const _Float16* pa = Ah + (size_t)kblk * 256 + n16 * 8;
      half8 a0 = *(const half8*)pa;
      half8 a1 = *(const half8*)(pa + 128);
      acc[0][0] = __builtin_amdgcn_mfma_f32_16x16x32_f16(a0, bhA, acc[0][0], 0, 0, 0);
      acc[1][0] = __builtin_amdgcn_mfma_f32_16x16x32_f16(a1, bhA, acc[1][0], 0, 0, 0);
      acc[0][1] = __builtin_amdgcn_mfma_f32_16x16x32_f16(a0, bhB, acc[0][1], 0, 0, 0);
      acc[1][1] = __builtin_amdgcn_mfma_f32_16x16x32_f16(a1, bhB, acc[1][1], 0, 0, 0);
    }
  }
#pragma unroll
  for (int mt = 0; mt < 2; mt++) {
#pragma unroll
    for (int reg = 0; reg < 4; reg++) {
      int o = mt * 16 + quad * 4 + reg;
      if (o < 27) {
        float bo = b_off[o];
#pragma unroll
        for (int nf = 0; nf < 2; nf++) {
          int w = w0 + nf * 16 + n16;
          om[((size_t)(b * 27 + o) << 14) + (h << 7) + w] = acc[mt][nf][reg] + bo;
        }
      }
    }
  }
}

// ---------------------------------------------------------------------------
// P3: deformable sampling + mask + depthwise, f16 gather + v_dot2_f32_f16.
// Per tap per lane (4 ch): 4x8B loads, 8 v_perm corner-pair packs, 8 dot2,
// 4 dw-fma. Bilinear weights pre-packed as half2 pairs in LDS.
// ---------------------------------------------------------------------------
__global__ __launch_bounds__(256) void k_sample(const unsigned short* __restrict__ xh,
                                                const float* __restrict__ om,
                                                const float* __restrict__ w_dw,
                                                const float* __restrict__ b_dw,
                                                unsigned short* __restrict__ out1h) {
  __shared__ int s_base[8][9], s_dxs[8][9], s_dys[8][9];
  __shared__ unsigned int s_wp[8][9][2];   // packed half2 (w00,w01),(w10,w11)
  int tid = threadIdx.x;
  int bid = blockIdx.x;
  int n0 = ((bid & 7) * 1024 + (bid >> 3)) * 8;   // XCD-contiguous bands
  if (tid < 72) {
    int pix = tid / 9, k = tid - pix * 9;
    int n = n0 + pix;
    int b = n >> 14, rem = n & 16383;
    int h = rem >> 7, w = rem & 127;
    const float* op = om + b * 27 * HWP + rem;
    float dy = op[(2 * k) * HWP];
    float dx = op[(2 * k + 1) * HWP];
    float mv = op[(18 + k) * HWP];
    mv = 1.0f / (1.0f + __expf(-mv));
    float py = (float)(h + k / 3 - 1) + dy;
    float px = (float)(w + k % 3 - 1) + dx;
    float y0f = floorf(py), x0f = floorf(px);
    float wy = py - y0f, wx = px - x0f;
    int y0 = (int)y0f, x0 = (int)x0f;
    int y1 = y0 + 1, x1 = x0 + 1;
    float v00 = (y0 >= 0 && y0 < HH && x0 >= 0 && x0 < WW) ? 1.f : 0.f;
    float v01 = (y0 >= 0 && y0 < HH && x1 >= 0 && x1 < WW) ? 1.f : 0.f;
    float v10 = (y1 >= 0 && y1 < HH && x0 >= 0 && x0 < WW) ? 1.f : 0.f;
    float v11 = (y1 >= 0 && y1 < HH && x1 >= 0 && x1 < WW) ? 1.f : 0.f;
    int y0c = min(max(y0, 0), HH - 1), y1c = min(max(y1, 0), HH - 1);
    int x0c = min(max(x0, 0), WW - 1), x1c = min(max(x1, 0), WW - 1);
    s_base[pix][k] = ((b * HH + y0c) * WW + x0c) * CC;
    s_dxs[pix][k] = (x1c - x0c) * CC;
    s_dys[pix][k] = (y1c - y0c) * WW * CC;
    float w00 = (1.f - wy) * (1.f - wx) * mv * v00;
    float w01 = (1.f - wy) * wx * mv * v01;
    float w10 = wy * (1.f - wx) * mv * v10;
    float w11 = wy * wx * mv * v11;
    s_wp[pix][k][0] = (unsigned int)f2h_bits(w00) | ((unsigned int)f2h_bits(w01) << 16);
    s_wp[pix][k][1] = (unsigned int)f2h_bits(w10) | ((unsigned int)f2h_bits(w11) << 16);
  }
  __syncthreads();
  int wv = tid >> 6, lane = tid & 63;
  int pix = wv * 2 + (lane >> 5);
  int cl = lane & 31;
  int c0 = cl * 4;
  int n = n0 + pix;

  // depthwise weights for channels c0..c0+3 (fp32)
  float4 wk4[9];
#pragma unroll
  for (int i = 0; i < 9; i++) wk4[i] = *(const float4*)(w_dw + c0 * 9 + i * 4);
  const float* wkf = (const float*)wk4;   // wkf[j*9 + k]

  float acc0 = 0.f, acc1 = 0.f, acc2v = 0.f, acc3 = 0.f;
#pragma unroll
  for (int k = 0; k < 9; k++) {
    int base = s_base[pix][k] + c0;
    int dxs = s_dxs[pix][k], dys = s_dys[pix][k];
    uint2 a00 = *(const uint2*)(xh + base);
    uint2 a01 = *(const uint2*)(xh + base + dxs);
    uint2 a10 = *(const uint2*)(xh + base + dys);
    uint2 a11 = *(const uint2*)(xh + base + dys + dxs);
    half2t wt = u2h2(s_wp[pix][k][0]);
    half2t wb = u2h2(s_wp[pix][k][1]);
    // pack per-channel corner pairs: (top0|top1) and (bot0|bot1)
    unsigned int t0 = __builtin_amdgcn_perm(a01.x, a00.x, 0x05040100u);
    unsigned int t1 = __builtin_amdgcn_perm(a01.x, a00.x, 0x07060302u);
    unsigned int t2 = __builtin_amdgcn_perm(a01.y, a00.y, 0x05040100u);
    unsigned int t3 = __builtin_amdgcn_perm(a01.y, a00.y, 0x07060302u);
    unsigned int b0 = __builtin_amdgcn_perm(a11.x, a10.x, 0x05040100u);
    unsigned int b1 = __builtin_amdgcn_perm(a11.x, a10.x, 0x07060302u);
    unsigned int b2 = __builtin_amdgcn_perm(a11.y, a10.y, 0x05040100u);
    unsigned int b3 = __builtin_amdgcn_perm(a11.y, a10.y, 0x07060302u);
    float v0 = __builtin_amdgcn_fdot2(u2h2(b0), wb, __builtin_amdgcn_fdot2(u2h2(t0), wt, 0.f, false), false);
    float v1 = __builtin_amdgcn_fdot2(u2h2(b1), wb, __builtin_amdgcn_fdot2(u2h2(t1), wt, 0.f, false), false);
    float v2 = __builtin_amdgcn_fdot2(u2h2(b2), wb, __builtin_amdgcn_fdot2(u2h2(t2), wt, 0.f, false), false);
    float v3 = __builtin_amdgcn_fdot2(u2h2(b3), wb, __builtin_amdgcn_fdot2(u2h2(t3), wt, 0.f, false), false);
    acc0 = fmaf(v0, wkf[0 * 9 + k], acc0);
    acc1 = fmaf(v1, wkf[1 * 9 + k], acc1);
    acc2v = fmaf(v2, wkf[2 * 9 + k], acc2v);
    acc3 = fmaf(v3, wkf[3 * 9 + k], acc3);
  }
  float4 bd = *(const float4*)(b_dw + c0);
  acc0 += bd.x; acc1 += bd.y; acc2v += bd.z; acc3 += bd.w;
  ushort4 ov;
  ov.x = f2h_bits(acc0);
  ov.y = f2h_bits(acc1);
  ov.z = f2h_bits(acc2v);
  ov.w = f2h_bits(acc3);
  *(ushort4*)(out1h + (size_t)n * CC + c0) = ov;
}

// ---------------------------------------------------------------------------
// P4: pointwise GEMM, f16 MFMA. Block = 4 waves; block tile 256o x 64n.
// ---------------------------------------------------------------------------
__global__ __launch_bounds__(256) void k_pw_mfma(const _Float16* __restrict__ Apw,
                                                 const _Float16* __restrict__ out1h,
                                                 const float* __restrict__ bpw,
                                                 float* __restrict__ out) {
  int bid = blockIdx.x;
  int n0 = ((bid & 7) * 128 + (bid >> 3)) * 64;
  int tid = threadIdx.x;
  int wv = tid >> 6, lane = tid & 63;
  int n16 = lane & 15, quad = lane >> 4;
  int obase = wv * 64;

  floatx4 acc[4][4] = {};   // [mf][nf]
#pragma unroll
  for (int cs = 0; cs < 4; cs++) {
    half8 af[4], bf[4];
#pragma unroll
    for (int mf = 0; mf < 4; mf++) {
      const _Float16* pa = Apw + ((size_t)(cs * 4 + quad) * 256 + obase + mf * 16 + n16) * 8;
      af[mf] = *(const half8*)pa;
    }
#pragma unroll
    for (int nf = 0; nf < 4; nf++) {
      const _Float16* pb = out1h + (size_t)(n0 + nf * 16 + n16) * CC + cs * 32 + quad * 8;
      bf[nf] = *(const half8*)pb;
    }
#pragma unroll
    for (int mf = 0; mf < 4; mf++)
#pragma unroll
      for (int nf = 0; nf < 4; nf++)
        acc[mf][nf] = __builtin_amdgcn_mfma_f32_16x16x32_f16(af[mf], bf[nf], acc[mf][nf], 0, 0, 0);
  }
  int b = n0 >> 14;
#pragma unroll
  for (int mf = 0; mf < 4; mf++) {
#pragma unroll
    for (int reg = 0; reg < 4; reg++) {
      int o = obase + mf * 16 + quad * 4 + reg;
      float bo = bpw[o];
#pragma unroll
      for (int nf = 0; nf < 4; nf++) {
        int n = n0 + nf * 16 + n16;
        int hw = n & 16383;
        out[((size_t)(b * OO + o) << 14) + hw] = acc[mf][nf][reg] + bo;
      }
    }
  }
}

// ---------------------------------------------------------------------------
extern "C" void kernel_launch(void* const* d_in, const int* in_sizes, int n_in,
                              void* d_out, int out_size, void* d_ws, size_t ws_size,
                              hipStream_t stream) {
  const float* x     = (const float*)d_in[0];
  const float* w_off = (const float*)d_in[1];
  const float* b_off = (const float*)d_in[2];
  const float* w_dw  = (const float*)d_in[3];
  const float* b_dw  = (const float*)d_in[4];
  const float* w_pw  = (const float*)d_in[5];
  const float* b_pw  = (const float*)d_in[6];
  float* out = (float*)d_out;
  float* ws  = (float*)d_ws;

  // d_out scratch (dead before k_pw_mfma writes): xh f16 NHWC (16.8 MB)
  _Float16* xh = (_Float16*)out;

  // ws layout (float offsets):
  //   om    : [0, 1769472)
  //   out1h : f16, 8388608 elems = 4194304 floats -> [1769472, 5963776)
  //   Ah    : f16 36864  -> at 5963776            (AFTER out1h — r5 bug fixed)
  //   Apw   : f16 32768
  float* om = ws;
  _Float16* out1h = (_Float16*)(ws + 1769472);
  _Float16* Ah = (_Float16*)(ws + 5963776);
  _Float16* Apw = Ah + 36864;

  k_transpose<<<dim3(4, 128, 5), 256, 0, stream>>>(x, w_off, w_pw,
                                                   (unsigned int*)xh, Ah, Apw);
  k_offconv_mfma<<<512, 256, 0, stream>>>(xh, Ah, b_off, om);
  k_sample<<<8192, 256, 0, stream>>>((const unsigned short*)xh, om, w_dw, b_dw,
                                     (unsigned short*)out1h);
  k_pw_mfma<<<1024, 256, 0, stream>>>(Apw, out1h, b_pw, out);
}